// Round 4
// baseline (451.749 us; speedup 1.0000x reference)
//
#include <hip/hip_runtime.h>

// Persistent-RNN v3: 256 blocks (1/CU) x 256 threads (4 waves, 1/SIMD).
// Each block owns 16 batch rows for all 200 timesteps.
// 4 waves x 5 N-tiles: weights (w_hh/w_ih f16 half8 fragments) fully
// register-resident (~280 regs -> VGPR+AGPR, budget 512 via launch_bounds(256,1)).
// h+xe double-buffered in LDS, XOR-swizzled (byte ^= (row&7)<<4), row stride
// 1792 B (multiple of 128 B) -> balanced banks for ds_read_b128.
// MFMA 16x16x32_f16: A/B: k = 8*(lane>>4)+j contiguous; D: col=lane&15, row=4g+j.

#define SEQ    200
#define BATCHN 4096
#define EMBD   100
#define HIDN   300

#define KCH   10      // K-chunks of 32 covering hidden (320)
#define KCE   4       // K-chunks of 32 covering emb (128)
#define XE0B  640     // xe byte offset within a buffer (320 f16)
#define BUFB  896     // one buffer: 448 f16 = 896 B
#define SROWB 1792    // row stride bytes (2 buffers, multiple of 128)
#define ROWS  16
#define NTMAX 5

typedef _Float16 half8 __attribute__((ext_vector_type(8)));
typedef float    f32x4 __attribute__((ext_vector_type(4)));

static __device__ __forceinline__ f32x4 f4z() { f32x4 z = {0.f,0.f,0.f,0.f}; return z; }

static __device__ __forceinline__ half8 h8cvt(f32x4 a, f32x4 b) {
  half8 h;
  h[0]=(_Float16)a[0]; h[1]=(_Float16)a[1]; h[2]=(_Float16)a[2]; h[3]=(_Float16)a[3];
  h[4]=(_Float16)b[0]; h[5]=(_Float16)b[1]; h[6]=(_Float16)b[2]; h[7]=(_Float16)b[3];
  return h;
}

// Load 8 f16 of row[k0..k0+7], zero-padded past kmax (kmax % 4 == 0).
static __device__ __forceinline__ half8 loadw(const float* row, int k0, int kmax, bool nv) {
  f32x4 a = (nv && (k0 + 3 < kmax)) ? *(const f32x4*)(row + k0)     : f4z();
  f32x4 b = (nv && (k0 + 7 < kmax)) ? *(const f32x4*)(row + k0 + 4) : f4z();
  return h8cvt(a, b);
}

static __device__ __forceinline__ float tanh_fast(float x) {
  float e = __builtin_amdgcn_exp2f(x * 2.8853900817779268f);  // exp(2x)
  float r = __builtin_amdgcn_rcpf(e + 1.0f);
  return __builtin_fmaf(-2.0f, r, 1.0f);
}

#define MFMA32(A,B,C) __builtin_amdgcn_mfma_f32_16x16x32_f16((A),(B),(C),0,0,0)

// A-fragment read: row r, byte offset boff within row, swizzled.
#define AREAD(boff) (*(const half8*)(lds_base + ((boff) ^ swz)))

#define STEP_BODY(NT_) do {                                                   \
    _Pragma("unroll")                                                         \
    for (int c = 0; c < KCH; c++) {                                           \
      const half8 a = AREAD(rbuf + c * 64 + g16);                             \
      acc[0] = MFMA32(a, whh[c][0], acc[0]);                                  \
      acc[1] = MFMA32(a, whh[c][1], acc[1]);                                  \
      acc[2] = MFMA32(a, whh[c][2], acc[2]);                                  \
      acc[3] = MFMA32(a, whh[c][3], acc[3]);                                  \
      if (NT_ == 5) acc[4] = MFMA32(a, whh[c][4], acc[4]);                    \
    }                                                                         \
    _Pragma("unroll")                                                         \
    for (int c = 0; c < KCE; c++) {                                           \
      const half8 a = AREAD(rbuf + XE0B + c * 64 + g16);                      \
      acc[0] = MFMA32(a, wih[c][0], acc[0]);                                  \
      acc[1] = MFMA32(a, wih[c][1], acc[1]);                                  \
      acc[2] = MFMA32(a, wih[c][2], acc[2]);                                  \
      acc[3] = MFMA32(a, wih[c][3], acc[3]);                                  \
      if (NT_ == 5) acc[4] = MFMA32(a, wih[c][4], acc[4]);                    \
    }                                                                         \
  } while (0)

__global__ __launch_bounds__(256, 1)
void rnn_fused(const int* __restrict__ x, const float* __restrict__ emb,
               const float* __restrict__ w_ih, const float* __restrict__ w_hh,
               const float* __restrict__ b_ih, const float* __restrict__ b_hh,
               const float* __restrict__ fc1w, const float* __restrict__ fc1b,
               const float* __restrict__ fc2w, const float* __restrict__ fc2b,
               float* __restrict__ out)
{
  __shared__ __align__(128) char s_lds[ROWS * SROWB];  // 2 x (h 320 | xe 128) f16, swizzled
  __shared__ __align__(16) float h1f[ROWS][257];       // fc1 output
  __shared__ int x_lds[SEQ][16];

  const int tid  = (int)threadIdx.x;
  const int lane = tid & 63;
  const int wv   = tid >> 6;
  const int r    = lane & 15;   // A-row / B-col / D-col lane index
  const int g    = lane >> 4;   // k-group 0..3 (k = 8g + j)
  const int g16  = 16 * g;
  const int base = (int)blockIdx.x * ROWS;
  const int swz  = (r & 7) << 4;

  // N-tile assignment: 19 tiles of 16 -> waves 0..2 get 5, wave 3 gets 4
  const int t0    = wv * NTMAX;
  const int ntile = (wv < 3) ? 5 : 4;

  // ---- stage x indices for this block's 16 rows (all 200 steps)
  for (int i = tid; i < SEQ * 16; i += 256)
    x_lds[i >> 4][i & 15] = x[(i >> 4) * BATCHN + base + (i & 15)];
  // ---- zero both h/xe buffers (padding cols must stay zero)
  for (int i = tid; i < ROWS * SROWB / 4; i += 256)
    ((int*)s_lds)[i] = 0;

  // ---- resident weight fragments (f16) + bias
  half8 whh[KCH][NTMAX];
  half8 wih[KCE][NTMAX];
  float bias[NTMAX];
  #pragma unroll
  for (int tt = 0; tt < NTMAX; tt++) {
    const int n = (t0 + tt) * 16 + r;
    const bool nv = (tt < ntile) && (n < HIDN);
    bias[tt] = nv ? (b_ih[n] + b_hh[n]) : 0.f;
    #pragma unroll
    for (int c = 0; c < KCH; c++)
      whh[c][tt] = loadw(w_hh + (long)n * HIDN, c * 32 + 8 * g, HIDN, nv);
    #pragma unroll
    for (int c = 0; c < KCE; c++)
      wih[c][tt] = loadw(w_ih + (long)n * EMBD, c * 32 + 8 * g, EMBD, nv);
  }

  // xe gather: 256 lanes, each owns (row rr, half8 slot s): covers 16x16 slots
  const int rr = r;                 // batch row this lane stages
  const int sl = wv * 4 + g;        // half8 slot 0..15 (k0 = 8*sl)
  const int k0 = 8 * sl;
  char* const lds_base = s_lds + r * SROWB;   // A-read base (row r)
  char* const xw_base  = s_lds + rr * SROWB;  // xe-write base (row rr)

  __syncthreads();

  // ---- pre-stage xe(t=0) into buffer 0
  {
    const int idx = x_lds[0][rr];
    const float* erow = emb + (long)idx * EMBD;
    f32x4 a = (k0 + 3 < EMBD) ? *(const f32x4*)(erow + k0)     : f4z();
    f32x4 b = (k0 + 7 < EMBD) ? *(const f32x4*)(erow + k0 + 4) : f4z();
    *(half8*)(xw_base + ((XE0B + 16 * sl) ^ ((rr & 7) << 4))) = h8cvt(a, b);
  }
  __syncthreads();

  // =========================== main scan ===========================
  #pragma unroll 2
  for (int t = 0; t < SEQ; t++) {
    const int rbuf = (t & 1) * BUFB;          // read buffer byte offset
    const int wbuf = ((t + 1) & 1) * BUFB;    // write buffer byte offset

    // issue next-step emb gathers early (latency hides under MFMAs)
    const int tn = (t + 1 < SEQ) ? t + 1 : t;
    const int idx = x_lds[tn][rr];
    const float* erow = emb + (long)idx * EMBD;
    f32x4 xga = (k0 + 3 < EMBD) ? *(const f32x4*)(erow + k0)     : f4z();
    f32x4 xgb = (k0 + 7 < EMBD) ? *(const f32x4*)(erow + k0 + 4) : f4z();

    f32x4 acc[NTMAX];
    #pragma unroll
    for (int tt = 0; tt < NTMAX; tt++) {
      f32x4 v = {bias[tt], bias[tt], bias[tt], bias[tt]};
      acc[tt] = v;
    }

    if (ntile == 5) { STEP_BODY(5); } else { STEP_BODY(4); }

    // stage xe(t+1) into the other buffer (other buffer: no reader conflict)
    *(half8*)(xw_base + ((wbuf + XE0B + 16 * sl) ^ ((rr & 7) << 4))) = h8cvt(xga, xgb);

    // h(t+1) = tanh(pre-act); D: row m = 4g+j, col n = tile*16 + r
    #pragma unroll
    for (int tt = 0; tt < NTMAX; tt++) {
      if (tt < ntile) {
        const int n = (t0 + tt) * 16 + r;
        if (n < HIDN) {
          #pragma unroll
          for (int j = 0; j < 4; j++) {
            const int m = 4 * g + j;
            *(_Float16*)(s_lds + m * SROWB + ((wbuf + 2 * n) ^ ((m & 7) << 4)))
                = (_Float16)tanh_fast(acc[tt][j]);
          }
        }
      }
    }
    __syncthreads();   // one barrier/step: step-t reads done before step-t+1 writes
  }

  // =========================== fc1 (relu) ===========================
  {
    const int fbuf = (SEQ & 1) * BUFB;   // h(SEQ) lives here (SEQ even -> buf 0)
    f32x4 acc1[4];
    const int f0 = wv * 4;   // 16 n-tiles over 4 waves
    #pragma unroll
    for (int ft = 0; ft < 4; ft++) {
      const float bb = fc1b[(f0 + ft) * 16 + r];
      f32x4 v = {bb, bb, bb, bb};
      acc1[ft] = v;
    }
    #pragma unroll
    for (int c = 0; c < KCH; c++) {
      const half8 a = AREAD(fbuf + c * 64 + g16);
      #pragma unroll
      for (int ft = 0; ft < 4; ft++) {
        const int n = (f0 + ft) * 16 + r;
        const half8 b = loadw(fc1w + (long)n * HIDN, c * 32 + 8 * g, HIDN, true);
        acc1[ft] = MFMA32(a, b, acc1[ft]);
      }
    }
    #pragma unroll
    for (int ft = 0; ft < 4; ft++) {
      const int n = (f0 + ft) * 16 + r;
      #pragma unroll
      for (int j = 0; j < 4; j++) {
        const float v = acc1[ft][j];
        h1f[4 * g + j][n] = v > 0.f ? v : 0.f;
      }
    }
  }
  __syncthreads();

  // =========================== fc2 (fp32 scalar) ===========================
  if (wv == 0 && lane < 48) {
    const int m = lane / 3;
    const int n = lane - 3 * m;
    float s = fc2b[n];
    for (int k = 0; k < 256; k++)
      s = __builtin_fmaf(h1f[m][k], fc2w[n * 256 + k], s);
    out[(base + m) * 3 + n] = s;
  }
}

extern "C" void kernel_launch(void* const* d_in, const int* in_sizes, int n_in,
                              void* d_out, int out_size, void* d_ws, size_t ws_size,
                              hipStream_t stream) {
  (void)in_sizes; (void)n_in; (void)d_ws; (void)ws_size; (void)out_size;
  const int*   x   = (const int*)d_in[0];
  const float* emb = (const float*)d_in[1];
  const float* wih = (const float*)d_in[2];
  const float* whh = (const float*)d_in[3];
  const float* bih = (const float*)d_in[4];
  const float* bhh = (const float*)d_in[5];
  const float* f1w = (const float*)d_in[6];
  const float* f1b = (const float*)d_in[7];
  const float* f2w = (const float*)d_in[8];
  const float* f2b = (const float*)d_in[9];
  rnn_fused<<<BATCHN / ROWS, 256, 0, stream>>>(
      x, emb, wih, whh, bih, bhh, f1w, f1b, f2w, f2b, (float*)d_out);
}

// Round 9
// 333.694 us; speedup vs baseline: 1.3538x; 1.3538x over previous
//
#include <hip/hip_runtime.h>

// Persistent-RNN v6 = R2 structure (known-correct) + launch_bounds(512,1).
// 256 blocks (1/CU) x 512 threads (8 waves, 2/SIMD).
// R2's only real defect was the 128-VGPR cap from launch_bounds(512,2):
// weights (~170 regs/wave) spilled to scratch (54 MB WRITE_SIZE). (512,1)
// raises the cap to 256 arch VGPRs -> fragments stay register-resident.
// K=32 MFMA (mfma_f32_16x16x32_f16): A/B: k = 8*(lane>>4)+j contiguous;
// D: col=lane&15, row=4*(lane>>4)+j. h+xe double-buffered in LDS, one
// barrier/step. Row stride 904 f16 = 1808 B == 16 mod 128 -> b128 A-reads
// are bank-uniform (8 dwords/bank); residual conflicts are the b16 h-writes.

#define SEQ    200
#define BATCHN 4096
#define EMBD   100
#define HIDN   300

#define KCH   10     // K-chunks of 32 covering hidden (320)
#define KCE   4      // K-chunks of 32 covering emb (128)
#define XE0   320    // xe column offset within a buffer
#define BSPAN 448    // one buffer span (320 h + 128 xe)
#define SROW  904    // 2*BSPAN + 8 pad (f16 elems; 1808 B/row)
#define ROWS  16

typedef _Float16 half8 __attribute__((ext_vector_type(8)));
typedef float    f32x4 __attribute__((ext_vector_type(4)));

static __device__ __forceinline__ f32x4 f4z() { f32x4 z = {0.f, 0.f, 0.f, 0.f}; return z; }

static __device__ __forceinline__ half8 h8cvt(f32x4 a, f32x4 b) {
  half8 h;
  h[0]=(_Float16)a[0]; h[1]=(_Float16)a[1]; h[2]=(_Float16)a[2]; h[3]=(_Float16)a[3];
  h[4]=(_Float16)b[0]; h[5]=(_Float16)b[1]; h[6]=(_Float16)b[2]; h[7]=(_Float16)b[3];
  return h;
}

// Load 8 f16 of row[k0..k0+7], zero-padded past kmax (kmax % 4 == 0 for all uses).
static __device__ __forceinline__ half8 loadw(const float* row, int k0, int kmax, bool nv) {
  f32x4 a = (nv && (k0 + 3 < kmax)) ? *(const f32x4*)(row + k0)     : f4z();
  f32x4 b = (nv && (k0 + 7 < kmax)) ? *(const f32x4*)(row + k0 + 4) : f4z();
  return h8cvt(a, b);
}

static __device__ __forceinline__ float tanh_fast(float x) {
  float e = __builtin_amdgcn_exp2f(x * 2.8853900817779268f);  // exp(2x)
  float r = __builtin_amdgcn_rcpf(e + 1.0f);
  return __builtin_fmaf(-2.0f, r, 1.0f);
}

#define MFMA32(A,B,C) __builtin_amdgcn_mfma_f32_16x16x32_f16((A),(B),(C),0,0,0)

#define STEP_BODY(NT_) do {                                                   \
    _Pragma("unroll")                                                         \
    for (int c = 0; c < KCH; c++) {                                           \
      const half8 a = *(const half8*)(ab + c * 32);                           \
      acc[0] = MFMA32(a, whh[c][0], acc[0]);                                  \
      acc[1] = MFMA32(a, whh[c][1], acc[1]);                                  \
      if (NT_ == 3) acc[2] = MFMA32(a, whh[c][2], acc[2]);                    \
    }                                                                         \
    _Pragma("unroll")                                                         \
    for (int c = 0; c < KCE; c++) {                                           \
      const half8 a = *(const half8*)(ab + XE0 + c * 32);                     \
      acc[0] = MFMA32(a, wih[c][0], acc[0]);                                  \
      acc[1] = MFMA32(a, wih[c][1], acc[1]);                                  \
      if (NT_ == 3) acc[2] = MFMA32(a, wih[c][2], acc[2]);                    \
    }                                                                         \
  } while (0)

__global__ __launch_bounds__(512, 1)
void rnn_fused(const int* __restrict__ x, const float* __restrict__ emb,
               const float* __restrict__ w_ih, const float* __restrict__ w_hh,
               const float* __restrict__ b_ih, const float* __restrict__ b_hh,
               const float* __restrict__ fc1w, const float* __restrict__ fc1b,
               const float* __restrict__ fc2w, const float* __restrict__ fc2b,
               float* __restrict__ out)
{
  __shared__ __align__(16) _Float16 s_lds[ROWS][SROW]; // 2 x (h 320 | xe 128)
  __shared__ __align__(16) float    h1f[ROWS][257];    // fc1 output
  __shared__ int x_lds[SEQ][16];

  const int tid  = (int)threadIdx.x;
  const int lane = tid & 63;
  const int wv   = tid >> 6;
  const int r    = lane & 15;   // A-row / B-col / D-col lane index
  const int g    = lane >> 4;   // k-group 0..3 (k = 8g + j)
  const int base = (int)blockIdx.x * ROWS;

  // N-tile assignment: 19 tiles of 16 -> waves 0..2 get 3, waves 3..7 get 2
  const int t0    = (wv < 3) ? wv * 3 : 9 + (wv - 3) * 2;
  const int ntile = (wv < 3) ? 3 : 2;

  // ---- stage x indices for this block's 16 rows (all 200 steps)
  for (int i = tid; i < SEQ * 16; i += 512)
    x_lds[i >> 4][i & 15] = x[(i >> 4) * BATCHN + base + (i & 15)];
  // ---- zero both h/xe buffers (padding cols must stay zero)
  for (int i = tid; i < ROWS * SROW; i += 512)
    (&s_lds[0][0])[i] = (_Float16)0.f;

  // ---- resident weight fragments (f16) + bias
  half8 whh[KCH][3];
  half8 wih[KCE][3];
  float bias[3];
  #pragma unroll
  for (int tt = 0; tt < 3; tt++) {
    const int n = (t0 + tt) * 16 + r;
    const bool nv = (tt < ntile) && (n < HIDN);
    bias[tt] = nv ? (b_ih[n] + b_hh[n]) : 0.f;
    #pragma unroll
    for (int c = 0; c < KCH; c++)
      whh[c][tt] = loadw(w_hh + (long)n * HIDN, c * 32 + 8 * g, HIDN, nv);
    #pragma unroll
    for (int c = 0; c < KCE; c++)
      wih[c][tt] = loadw(w_ih + (long)n * EMBD, c * 32 + 8 * g, EMBD, nv);
  }

  // xe gather duty: wave6 -> chunks 0..1, wave7 -> chunks 2..3
  const int gc0 = (wv - 6) * 2;

  __syncthreads();

  // ---- pre-stage xe(t=0) into buffer 0
  if (wv >= 6) {
    const int idx = x_lds[0][r];
    const float* erow = emb + (long)idx * EMBD;
    #pragma unroll
    for (int j = 0; j < 2; j++) {
      const int k0 = (gc0 + j) * 32 + 8 * g;
      f32x4 a = (k0 + 3 < EMBD) ? *(const f32x4*)(erow + k0)     : f4z();
      f32x4 b = (k0 + 7 < EMBD) ? *(const f32x4*)(erow + k0 + 4) : f4z();
      *(half8*)&s_lds[r][XE0 + k0] = h8cvt(a, b);
    }
  }
  __syncthreads();

  const _Float16* a_base = &s_lds[r][8 * g];

  // =========================== main scan ===========================
  #pragma unroll 2
  for (int t = 0; t < SEQ; t++) {
    const _Float16* ab = a_base + (t & 1) * BSPAN;    // read buffer
    const int nbuf = ((t + 1) & 1) * BSPAN;           // write buffer (col offset)

    // issue next-step emb gathers early (latency hides under MFMAs)
    f32x4 xg[2][2];
    if (wv >= 6) {
      const int tn = (t + 1 < SEQ) ? t + 1 : t;
      const int idx = x_lds[tn][r];
      const float* erow = emb + (long)idx * EMBD;
      #pragma unroll
      for (int j = 0; j < 2; j++) {
        const int k0 = (gc0 + j) * 32 + 8 * g;
        xg[j][0] = (k0 + 3 < EMBD) ? *(const f32x4*)(erow + k0)     : f4z();
        xg[j][1] = (k0 + 7 < EMBD) ? *(const f32x4*)(erow + k0 + 4) : f4z();
      }
    }

    f32x4 acc[3];
    #pragma unroll
    for (int tt = 0; tt < 3; tt++) {
      f32x4 v = {bias[tt], bias[tt], bias[tt], bias[tt]};
      acc[tt] = v;
    }

    if (ntile == 3) { STEP_BODY(3); } else { STEP_BODY(2); }

    // stage xe(t+1) into the other buffer (no reader conflict; barrier below)
    if (wv >= 6) {
      #pragma unroll
      for (int j = 0; j < 2; j++) {
        const int k0 = (gc0 + j) * 32 + 8 * g;
        *(half8*)&s_lds[r][nbuf + XE0 + k0] = h8cvt(xg[j][0], xg[j][1]);
      }
    }
    // h(t+1) = tanh(pre-act); D: row = 4g+j, col n = tile*16 + r
    #pragma unroll
    for (int tt = 0; tt < 3; tt++) {
      if (tt < ntile) {
        const int n = (t0 + tt) * 16 + r;
        if (n < HIDN) {
          #pragma unroll
          for (int j = 0; j < 4; j++)
            s_lds[4 * g + j][nbuf + n] = (_Float16)tanh_fast(acc[tt][j]);
        }
      }
    }
    __syncthreads();   // single barrier: separates step t reads from step t+1 writes
  }

  // =========================== fc1 (relu) ===========================
  {
    const _Float16* abf = a_base + (SEQ & 1) * BSPAN;  // h(SEQ) buffer
    f32x4 acc1[2];
    const int f0 = wv * 2;   // 16 n-tiles over 8 waves
    #pragma unroll
    for (int ft = 0; ft < 2; ft++) {
      const float bb = fc1b[(f0 + ft) * 16 + r];
      f32x4 v = {bb, bb, bb, bb};
      acc1[ft] = v;
    }
    #pragma unroll
    for (int c = 0; c < KCH; c++) {
      const half8 a = *(const half8*)(abf + c * 32);
      #pragma unroll
      for (int ft = 0; ft < 2; ft++) {
        const int n = (f0 + ft) * 16 + r;
        const half8 b = loadw(fc1w + (long)n * HIDN, c * 32 + 8 * g, HIDN, true);
        acc1[ft] = MFMA32(a, b, acc1[ft]);
      }
    }
    #pragma unroll
    for (int ft = 0; ft < 2; ft++) {
      const int n = (f0 + ft) * 16 + r;
      #pragma unroll
      for (int j = 0; j < 4; j++) {
        const float v = acc1[ft][j];
        h1f[4 * g + j][n] = v > 0.f ? v : 0.f;
      }
    }
  }
  __syncthreads();

  // =========================== fc2 (fp32 scalar) ===========================
  if (wv == 0 && lane < 48) {
    const int m = lane / 3;
    const int n = lane - 3 * m;
    float s = fc2b[n];
    for (int k = 0; k < 256; k++)
      s = __builtin_fmaf(h1f[m][k], fc2w[n * 256 + k], s);
    out[(base + m) * 3 + n] = s;
  }
}

extern "C" void kernel_launch(void* const* d_in, const int* in_sizes, int n_in,
                              void* d_out, int out_size, void* d_ws, size_t ws_size,
                              hipStream_t stream) {
  (void)in_sizes; (void)n_in; (void)d_ws; (void)ws_size; (void)out_size;
  const int*   x   = (const int*)d_in[0];
  const float* emb = (const float*)d_in[1];
  const float* wih = (const float*)d_in[2];
  const float* whh = (const float*)d_in[3];
  const float* bih = (const float*)d_in[4];
  const float* bhh = (const float*)d_in[5];
  const float* f1w = (const float*)d_in[6];
  const float* f1b = (const float*)d_in[7];
  const float* f2w = (const float*)d_in[8];
  const float* f2b = (const float*)d_in[9];
  rnn_fused<<<BATCHN / ROWS, 512, 0, stream>>>(
      x, emb, wih, whh, bih, bhh, f1w, f1b, f2w, f2b, (float*)d_out);
}